// Round 1
// baseline (67.846 us; speedup 1.0000x reference)
//
#include <hip/hip_runtime.h>

// LUT = [0,0,1,1,1,1,1,1,0,0] -> binary label is 1 iff class in [2,7]
__device__ __forceinline__ int lut_of(int c) {
    return (c >= 2 && c <= 7) ? 1 : 0;
}

// Per-row: CE contribution (max + log(sum exp) - x[tgt]) and binary mismatch.
__device__ __forceinline__ void row_stats(const float r[10], int tgt,
                                          float& ce_acc, unsigned int& mm_acc) {
    float m = r[0];
    int am = 0;
    #pragma unroll
    for (int j = 1; j < 10; ++j) {
        if (r[j] > m) { m = r[j]; am = j; }   // strict > keeps first-max (jnp.argmax)
    }
    float se = 0.0f;
    #pragma unroll
    for (int j = 0; j < 10; ++j) se += __expf(r[j] - m);
    // static-index select of r[tgt] (avoid runtime-indexed array -> scratch)
    float pt = r[0];
    #pragma unroll
    for (int j = 1; j < 10; ++j) pt = (tgt == j) ? r[j] : pt;
    ce_acc += m + __logf(se) - pt;
    mm_acc += (lut_of(am) != lut_of(tgt)) ? 1u : 0u;
}

__global__ void __launch_bounds__(256)
loss_main(const float* __restrict__ pred,
          const int* __restrict__ target,
          int nrows, int npairs,
          float* __restrict__ ce_sum,
          unsigned int* __restrict__ mm_sum) {
    float ce = 0.0f;
    unsigned int mm = 0u;

    const int tid    = blockIdx.x * blockDim.x + threadIdx.x;
    const int stride = gridDim.x * blockDim.x;

    // Each work item = 2 rows = 80 bytes = 5 aligned float4 loads.
    for (int p = tid; p < npairs; p += stride) {
        const float4* base = reinterpret_cast<const float4*>(pred) + (size_t)p * 5;
        float4 v0 = base[0];
        float4 v1 = base[1];
        float4 v2 = base[2];
        float4 v3 = base[3];
        float4 v4 = base[4];
        int t0 = target[2 * p];
        int t1 = target[2 * p + 1];

        const float r0[10] = {v0.x, v0.y, v0.z, v0.w, v1.x, v1.y, v1.z, v1.w, v2.x, v2.y};
        const float r1[10] = {v2.z, v2.w, v3.x, v3.y, v3.z, v3.w, v4.x, v4.y, v4.z, v4.w};

        row_stats(r0, t0, ce, mm);
        row_stats(r1, t1, ce, mm);
    }

    // Odd-row tail (not hit for N=2e6, kept for generality).
    if ((nrows & 1) && tid == 0) {
        const float* rp = pred + (size_t)(nrows - 1) * 10;
        float r[10];
        #pragma unroll
        for (int j = 0; j < 10; ++j) r[j] = rp[j];
        row_stats(r, target[nrows - 1], ce, mm);
    }

    // Wave-64 reduction
    #pragma unroll
    for (int off = 32; off > 0; off >>= 1) {
        ce += __shfl_down(ce, off);
        mm += __shfl_down(mm, off);
    }

    __shared__ float        s_ce[4];
    __shared__ unsigned int s_mm[4];
    const int wid  = threadIdx.x >> 6;
    const int lane = threadIdx.x & 63;
    if (lane == 0) { s_ce[wid] = ce; s_mm[wid] = mm; }
    __syncthreads();

    if (threadIdx.x == 0) {
        float        c = 0.0f;
        unsigned int t = 0u;
        const int nw = blockDim.x >> 6;
        for (int w = 0; w < nw; ++w) { c += s_ce[w]; t += s_mm[w]; }
        atomicAdd(ce_sum, c);
        atomicAdd(mm_sum, t);
    }
}

__global__ void loss_finalize(const float* __restrict__ ce_sum,
                              const unsigned int* __restrict__ mm_sum,
                              float* __restrict__ out, float inv_n) {
    // ce mean + 100 * mismatch-rate (exact collapse of clamped-log BCE on {0,1})
    out[0] = ce_sum[0] * inv_n + 100.0f * (float)mm_sum[0] * inv_n;
}

extern "C" void kernel_launch(void* const* d_in, const int* in_sizes, int n_in,
                              void* d_out, int out_size, void* d_ws, size_t ws_size,
                              hipStream_t stream) {
    const float* pred   = (const float*)d_in[0];
    const int*   target = (const int*)d_in[1];

    const int nrows  = in_sizes[0] / 10;
    const int npairs = nrows / 2;

    float*        ws_ce = (float*)d_ws;
    unsigned int* ws_mm = (unsigned int*)((char*)d_ws + sizeof(float));

    // Zero accumulators every call (harness does not re-poison between replays).
    hipMemsetAsync(d_ws, 0, 2 * sizeof(unsigned int), stream);

    int blocks = (npairs + 255) / 256;
    if (blocks > 2048) blocks = 2048;
    if (blocks < 1) blocks = 1;

    loss_main<<<blocks, 256, 0, stream>>>(pred, target, nrows, npairs, ws_ce, ws_mm);
    loss_finalize<<<1, 1, 0, stream>>>(ws_ce, ws_mm, (float*)d_out,
                                       1.0f / (float)nrows);
}